// Round 5
// baseline (86.786 us; speedup 1.0000x reference)
//
#include <hip/hip_runtime.h>
#include <math.h>

#define NPTS 10000
#define XPT 4              // x-points per thread in pass A
#define AXCH 10            // ceil(10000 / (256*XPT))

// ---------------------------------------------------------------------------
// Pass 0: pack y4[c][j] = (ya, yb, yc, -0.5*|y|^2) for each combo's y-set.
// combo c: dir=c>>1, b=c&1; y-set = (dir==0 ? pred : targ) batch b.
// Both pass A and pass B consume this SAME stored hy -> bit-consistent.
// ---------------------------------------------------------------------------
__global__ __launch_bounds__(256) void pack_y(
    const float* __restrict__ pred_pts, const float* __restrict__ targ_pts,
    float4* __restrict__ y4)
{
    const int idx = blockIdx.x * 256 + threadIdx.x;
    if (idx >= 4 * NPTS) return;
    const int c = idx / NPTS;
    const int j = idx - c * NPTS;
    const int dir = c >> 1, b = c & 1;
    const float* yp = (dir == 0 ? pred_pts : targ_pts) + (size_t)b * NPTS * 3;
    const float a  = yp[j * 3 + 0];
    const float bb = yp[j * 3 + 1];
    const float cc = yp[j * 3 + 2];
    y4[idx] = make_float4(a, bb, cc, -0.5f * (a * a + bb * bb + cc * cc));
}

// ---------------------------------------------------------------------------
// Pass A: partial max of m_j = dot(x,y_j) - 0.5|y_j|^2 over each slice.
// KEY: yq[j] is a wave-UNIFORM address -> compiler scalarizes to s_load into
// SGPRs (SALU pipe, prefetched across the unroll). No LDS, no syncthreads,
// no VMEM in the hot loop -> pure VALU issue at 3.5 instr/pair.
// ---------------------------------------------------------------------------
__global__ __launch_bounds__(256, 4) void knn_max(
    const float* __restrict__ pred_pts, const float* __restrict__ targ_pts,
    const float4* __restrict__ y4, float* __restrict__ wsM, int nslices)
{
    const int slice = NPTS / nslices;          // even for all ladder values
    const int c   = blockIdx.z;
    const int dir = c >> 1, b = c & 1;
    const float* xp = (dir == 0 ? targ_pts : pred_pts) + (size_t)b * NPTS * 3;
    const float4* __restrict__ yq = y4 + (size_t)c * NPTS;
    const int s = blockIdx.y;
    const int base = blockIdx.x * (256 * XPT) + threadIdx.x;

    float xx[XPT][3];
#pragma unroll
    for (int k = 0; k < XPT; ++k) {
        const int n = base + k * 256;
        const int nn = (n < NPTS) ? n : (NPTS - 1);   // clamp; discard on store
        xx[k][0] = xp[nn * 3 + 0];
        xx[k][1] = xp[nn * 3 + 1];
        xx[k][2] = xp[nn * 3 + 2];
    }
    float best[XPT];
#pragma unroll
    for (int k = 0; k < XPT; ++k) best[k] = -1e30f;

    const int js = s * slice, je = js + slice;
#pragma unroll 4
    for (int j = js; j < je; j += 2) {
        const float4 Y0 = yq[j];       // uniform -> s_load (SGPR broadcast)
        const float4 Y1 = yq[j + 1];
#pragma unroll
        for (int k = 0; k < XPT; ++k) {
            const float ma = fmaf(xx[k][0], Y0.x,
                             fmaf(xx[k][1], Y0.y,
                             fmaf(xx[k][2], Y0.z, Y0.w)));
            const float mb = fmaf(xx[k][0], Y1.x,
                             fmaf(xx[k][1], Y1.y,
                             fmaf(xx[k][2], Y1.z, Y1.w)));
            best[k] = fmaxf(fmaxf(best[k], ma), mb);   // -> v_max3_f32
        }
    }
#pragma unroll
    for (int k = 0; k < XPT; ++k) {
        const int n = base + k * 256;
        if (n < NPTS)
            wsM[((size_t)(c * nslices + s)) * NPTS + n] = best[k];
    }
}

// ---------------------------------------------------------------------------
// Pass B: 8-lane group per x-point. Slice-select from pass-A maxima (tie ->
// smaller s), lane-parallel rescan of winning slice via y4 (identical fmaf
// chain and identical stored hy -> bit-consistent with pass A; tie -> smaller
// j = exact first-occurrence argmax), then Welsch + normal terms.
// ---------------------------------------------------------------------------
__global__ __launch_bounds__(256) void finalize(
    const float* __restrict__ pred_pts, const float* __restrict__ pred_nrm,
    const float* __restrict__ targ_pts, const float* __restrict__ targ_nrm,
    const float4* __restrict__ y4, const float* __restrict__ wsM,
    float2* __restrict__ wsB, int nslices)
{
    const int c   = blockIdx.y;
    const int dir = c >> 1, b = c & 1;
    const float* xp = (dir == 0 ? targ_pts : pred_pts) + (size_t)b * NPTS * 3;
    const float* xn = (dir == 0 ? targ_nrm : pred_nrm) + (size_t)b * NPTS * 3;
    const float* yn = (dir == 0 ? pred_nrm : targ_nrm) + (size_t)b * NPTS * 3;
    const float4* __restrict__ yq = y4 + (size_t)c * NPTS;

    const int lane = threadIdx.x & 7;
    const int n = blockIdx.x * 32 + (threadIdx.x >> 3);

    float t0 = 0.f, t1 = 0.f;
    if (n < NPTS) {
        float bm = -1e30f;
        int   bs = 1 << 30;
        for (int s = lane; s < nslices; s += 8) {
            const float m = wsM[((size_t)(c * nslices + s)) * NPTS + n];
            if (m > bm) { bm = m; bs = s; }
        }
#pragma unroll
        for (int w = 1; w < 8; w <<= 1) {
            const float mo = __shfl_xor(bm, w);
            const int   so = __shfl_xor(bs, w);
            if (mo > bm || (mo == bm && so < bs)) { bm = mo; bs = so; }
        }
        const float a  = xp[n * 3 + 0];
        const float bb = xp[n * 3 + 1];
        const float cc = xp[n * 3 + 2];
        const int slice = NPTS / nslices;
        const int j0 = bs * slice;
        float rb = -1e30f;
        int bidx = 1 << 30;
        for (int j = j0 + lane; j < j0 + slice; j += 8) {
            const float4 Y = yq[j];            // coalesced dwordx4
            const float m = fmaf(a, Y.x, fmaf(bb, Y.y, fmaf(cc, Y.z, Y.w)));
            if (m > rb) { rb = m; bidx = j; }
        }
#pragma unroll
        for (int w = 1; w < 8; w <<= 1) {
            const float mo = __shfl_xor(rb, w);
            const int   jo = __shfl_xor(bidx, w);
            if (mo > rb || (mo == rb && jo < bidx)) { rb = mo; bidx = jo; }
        }
        if (lane == 0) {
            const float hx = -0.5f * (a * a + bb * bb + cc * cc);
            float d2 = -2.0f * (rb + hx);
            d2 = fmaxf(d2, 0.0f);
            const float w = __expf(-(d2 * d2) * (1.0f / 0.18f));  // 2*ALPHA^2
            t0 = w * d2;
            const float nx0 = xn[n * 3 + 0], nx1 = xn[n * 3 + 1], nx2 = xn[n * 3 + 2];
            const float ny0 = yn[(size_t)bidx * 3 + 0];
            const float ny1 = yn[(size_t)bidx * 3 + 1];
            const float ny2 = yn[(size_t)bidx * 3 + 2];
            const float nnx = fmaxf(sqrtf(nx0 * nx0 + nx1 * nx1 + nx2 * nx2), 1e-6f);
            const float nny = fmaxf(sqrtf(ny0 * ny0 + ny1 * ny1 + ny2 * ny2), 1e-6f);
            const float cosv = (nx0 * ny0 + nx1 * ny1 + nx2 * ny2) / (nnx * nny);
            t1 = 1.0f - fabsf(cosv);
        }
    }

    __shared__ float r0[256], r1[256];
    r0[threadIdx.x] = t0;
    r1[threadIdx.x] = t1;
    __syncthreads();
    for (int st = 128; st > 0; st >>= 1) {
        if (threadIdx.x < st) {
            r0[threadIdx.x] += r0[threadIdx.x + st];
            r1[threadIdx.x] += r1[threadIdx.x + st];
        }
        __syncthreads();
    }
    if (threadIdx.x == 0)
        wsB[blockIdx.y * gridDim.x + blockIdx.x] = make_float2(r0[0], r1[0]);
}

// ---------------------------------------------------------------------------
// Final deterministic reduction of the block partials.
// ---------------------------------------------------------------------------
__global__ __launch_bounds__(256) void reduce_final(
    const float2* __restrict__ wsB, int nblocks, float* __restrict__ out)
{
    __shared__ float r0[256], r1[256];
    const int t = threadIdx.x;
    float s0 = 0.f, s1 = 0.f;
    for (int i = t; i < nblocks; i += 256) {
        const float2 v = wsB[i];
        s0 += v.x;
        s1 += v.y;
    }
    r0[t] = s0; r1[t] = s1;
    __syncthreads();
    for (int st = 128; st > 0; st >>= 1) {
        if (t < st) { r0[t] += r0[t + st]; r1[t] += r1[t + st]; }
        __syncthreads();
    }
    if (t == 0) {
        out[0] = 0.5f * r0[0];                 // mean over B=2 of per-batch sums
        out[1] = r1[0] * (1.0f / 20000.0f);    // mean over B*N, both dirs
    }
}

extern "C" void kernel_launch(void* const* d_in, const int* in_sizes, int n_in,
                              void* d_out, int out_size, void* d_ws, size_t ws_size,
                              hipStream_t stream)
{
    const float* pred_pts = (const float*)d_in[0];
    const float* pred_nrm = (const float*)d_in[1];
    const float* targ_pts = (const float*)d_in[2];
    const float* targ_nrm = (const float*)d_in[3];
    float* out = (float*)d_out;

    const int BXCH = (NPTS + 31) / 32;   // 313 blocks per combo in pass B
    const size_t Y4B = (size_t)4 * NPTS * sizeof(float4);   // 640 KB

    // Largest slice count whose workspace (y4 + wsM + wsB) fits; all even.
    const int ladder[5] = {20, 10, 5, 4, 2};
    int ns = 2;
    for (int i = 0; i < 5; ++i) {
        const size_t need = Y4B + (size_t)4 * ladder[i] * NPTS * sizeof(float)
                          + (size_t)4 * BXCH * sizeof(float2) + 256;
        if (need <= ws_size) { ns = ladder[i]; break; }
    }

    float4* y4  = (float4*)d_ws;                        // 4*NPTS float4
    float*  wsM = (float*)((char*)d_ws + Y4B);          // 4*ns*NPTS floats
    float2* wsB = (float2*)(wsM + (size_t)4 * ns * NPTS);

    pack_y<<<(4 * NPTS + 255) / 256, 256, 0, stream>>>(pred_pts, targ_pts, y4);

    dim3 gA(AXCH, ns, 4);
    knn_max<<<gA, 256, 0, stream>>>(pred_pts, targ_pts, y4, wsM, ns);

    dim3 gB(BXCH, 4);
    finalize<<<gB, 256, 0, stream>>>(pred_pts, pred_nrm, targ_pts, targ_nrm,
                                     y4, wsM, wsB, ns);

    reduce_final<<<1, 256, 0, stream>>>(wsB, BXCH * 4, out);
}